// Round 19
// baseline (1043.661 us; speedup 1.0000x reference)
//
#include <hip/hip_runtime.h>
#include <hip/hip_bf16.h>

typedef unsigned short u16;
typedef __attribute__((ext_vector_type(8))) __bf16 bf16x8;
typedef __attribute__((ext_vector_type(8))) short short8;
typedef __attribute__((ext_vector_type(4))) float f32x4;

#define BB 4096
#define TT 19
#define INP 17
#define HH 1024
#define NE 4128          // 4096 permuted gate entries + 32 proj rows
#define NT_PROJ 15       // proj rows are staged/used by nt==15 blocks

// dynamic LDS map (u16 units): A dbuf 2x16384, B dbuf 2x16384, P dbuf 2x2048
// epilogue reuse: h tile [256][64] u16 -> A0 region; c tile [256][64] f32 ->
// A1 (rows 0..127) + B1 (rows 128..255) regions.
#define ABASE(b) ((b) * 16384)
#define BBASE(b) (32768 + (b) * 16384)
#define PBASE(b) (65536 + (b) * 2048)
#define LDS_BYTES 139264

#define FENCE asm volatile("" ::: "memory")

__device__ __forceinline__ u16 f2bfu(float f) {
    __hip_bfloat16 b = __float2bfloat16(f);
    return __builtin_bit_cast(unsigned short, b);
}
__device__ __forceinline__ float bfu2f(u16 u) {
    unsigned int x = ((unsigned int)u) << 16;
    return __builtin_bit_cast(float, x);
}
__device__ __forceinline__ float fast_sigmoid(float x) {
    return 1.f / (1.f + __expf(-x));
}
__device__ __forceinline__ float fast_tanh(float x) {
    float e = __expf(2.f * x);
    return (e - 1.f) / (e + 1.f);
}
__device__ __forceinline__ bf16x8 ldfrag(const u16* p) {
    return __builtin_bit_cast(bf16x8, *(const short8*)p);
}
// c-tile row base in u16 units (A1 for rows 0..127, B1 for 128..255)
__device__ __forceinline__ int cBase(int row) {
    return row < 128 ? 16384 + row * 128 : 49152 + (row - 128) * 128;
}
// async 16B global -> LDS (linear dest = wave base + lane*16)
__device__ __forceinline__ void cp16(const u16* l, const void* g) {
    __builtin_amdgcn_global_load_lds(
        (const __attribute__((address_space(1))) unsigned int*)g,
        (__attribute__((address_space(3))) unsigned int*)l, 16, 0, 0);
}

// ---------------- prep kernels ----------------
// wperm[NE][HH]: entry r of tile nt -> gate (r>>4)&3, hcol nt*64+(r>>6)*16+(r&15);
// rows 4096..4127 = W_lin rows (17 real + zero pad). grid MUST be 2064.
__global__ void prep_wperm(const float* __restrict__ Whh, const float* __restrict__ Wlin,
                           u16* __restrict__ wperm) {
    size_t idx = ((size_t)blockIdx.x * 256 + threadIdx.x) * 8;
    int R = (int)(idx >> 10);
    int k = (int)(idx & 1023);
    const float* src = nullptr;
    if (R < 4096) {
        int nt = R >> 8, r = R & 255;
        int qn = r >> 6, nf = (r >> 4) & 3, cj = r & 15;
        int hcol = nt * 64 + qn * 16 + cj;
        src = Whh + ((size_t)(nf * HH + hcol)) * HH + k;
    } else if (R - 4096 < INP) {
        src = Wlin + (size_t)(R - 4096) * HH + k;
    }
#pragma unroll
    for (int e = 0; e < 8; ++e) wperm[idx + e] = src ? f2bfu(src[e]) : (u16)0;
}

// wx64[NE][64]: same row permutation of W_ih, K padded 17->64. grid 1032.
__global__ void prep_wx64(const float* __restrict__ Wih, u16* __restrict__ wx64) {
    int idx = blockIdx.x * 256 + threadIdx.x;
    int R = idx >> 6, k = idx & 63;
    u16 v = 0;
    if (R < 4096 && k < INP) {
        int nt = R >> 8, r = R & 255;
        int qn = r >> 6, nf = (r >> 4) & 3, cj = r & 15;
        int hcol = nt * 64 + qn * 16 + cj;
        v = f2bfu(Wih[(size_t)(nf * HH + hcol) * INP + k]);
    }
    wx64[idx] = v;
}

// bias[4096] = b_ih + b_hh. grid 16.
__global__ void prep_bias(const float* __restrict__ bih, const float* __restrict__ bhh,
                          float* __restrict__ bias) {
    int idx = blockIdx.x * 256 + threadIdx.x;
    bias[idx] = bih[idx] + bhh[idx];
}

// xpad64[t][b][64] via LDS transpose: block stages 32 batch rows (32x323 f32)
// with fully-coalesced reads, then writes 19 t-slots as contiguous 4 KB runs.
// grid MUST be 128 (128 x 32 rows = 4096).
__global__ __launch_bounds__(256) void prep_x_t(const float* __restrict__ x,
                                                u16* __restrict__ xpad) {
    __shared__ float sx[32 * 323];          // 41,344 B
    const int tid = threadIdx.x;
    const int b0 = blockIdx.x * 32;
    for (int j = tid; j < 32 * 323; j += 256)
        sx[j] = x[(size_t)b0 * 323 + j];
    __syncthreads();
    for (int j = tid; j < TT * 32 * 64; j += 256) {
        int tt = j >> 11;                   // 0..18
        int r = (j >> 6) & 31;
        int c = j & 63;
        u16 v = (c < INP) ? f2bfu(sx[r * 323 + tt * 17 + c]) : (u16)0;
        xpad[((size_t)tt * BB + b0 + r) * 64 + c] = v;
    }
}

// tail projection: out_18 = h_19 @ W_lin^T + b_lin. grid 512 x 8 rows.
__global__ __launch_bounds__(256) void proj_tail(
    const u16* __restrict__ h, const u16* __restrict__ wlin,
    const float* __restrict__ blin, float* __restrict__ outp)
{
    __shared__ u16 sW[INP * 1032];          // 35,088 B
    __shared__ u16 sh[8 * 1032];            // 16,512 B
    const int tid = threadIdx.x;
    const int b0 = blockIdx.x * 8;
    for (int j = tid; j < INP * 128; j += 256) {
        int r = j >> 7, c = j & 127;
        *(short8*)&sW[r * 1032 + c * 8] = *(const short8*)&wlin[(size_t)r * HH + c * 8];
    }
    for (int j = tid; j < 8 * 128; j += 256) {
        int r = j >> 7, c = j & 127;
        *(short8*)&sh[r * 1032 + c * 8] = *(const short8*)&h[(size_t)(b0 + r) * HH + c * 8];
    }
    __syncthreads();
    const int row = tid >> 5;               // 0..7
    const int il = tid & 31;                // 0..31 (active < 17)
    if (il < INP) {
        float sum = 0.f;
        for (int k = 0; k < HH; k += 8) {
            short8 hv = *(const short8*)&sh[row * 1032 + k];
            short8 wv = *(const short8*)&sW[il * 1032 + k];
#pragma unroll
            for (int e = 0; e < 8; ++e)
                sum += bfu2f((u16)hv[e]) * bfu2f((u16)wv[e]);
        }
        outp[((size_t)(b0 + row) * TT + 18) * INP + il] = sum + blin[il];
    }
}

// ------- fused step kernel: 256x256, BK=64, 4-phase interleaved pipeline ----
// grid 256 = 16 mt x 16 nt (XCD 2D-chunked), 512 threads = 8 waves (2qr x 4qn).
// Layout/swizzle/staging/epilogue = r14-verbatim (proven, 393K conflicts).
// NEW: each K-tile runs as 4 phases {ds_read cluster; stage-issue (p0: A+2B,
// p1: 2B+P); barrier; lgkmcnt(0)+sched_barrier; setprio(1); 16 MFMA;
// setprio(0); [p3: vmcnt(0), covered by ~3 phases since last issue]; barrier}.
__global__ __launch_bounds__(512, 2) void lstm_step(
    const u16* __restrict__ h_in, u16* __restrict__ h_out,
    float* __restrict__ c_buf, const u16* __restrict__ wperm,
    const u16* __restrict__ wx64, const float* __restrict__ bias,
    const u16* __restrict__ xpad64, const float* __restrict__ blin,
    float* __restrict__ outp, float* __restrict__ h_fin,
    int t, int is_last, int tail)
{
    extern __shared__ u16 lds[];

    const int tid = threadIdx.x;
    const int lane = tid & 63;
    const int wv = tid >> 6;
    const int qr = wv >> 2, qn = wv & 3;
    const int r16 = lane & 15, s4 = lane >> 4;

    int mt, nt;
    if (tail) { mt = blockIdx.x; nt = NT_PROJ; }
    else {
        const int xcd = blockIdx.x & 7, local = blockIdx.x >> 3;
        mt = (xcd >> 2) * 8 + (local & 7);
        nt = (xcd & 3) * 4 + (local >> 3);
    }
    const int m0 = mt * 256;
    const size_t R0 = (size_t)nt * 256;
    const bool my_proj = (nt == NT_PROJ) && (qn < 2);
    const int NK = (tail || t > 0) ? 17 : 1;   // t==0: gates = x@Wih + b only

    int srow[4], sgc[4];
#pragma unroll
    for (int i = 0; i < 4; ++i) {
        int d = tid + i * 512;
        srow[i] = d >> 3;
        sgc[i] = (d & 7) ^ (srow[i] & 7);
    }
    const u16* hA[4];
    const u16* wB[4];
#pragma unroll
    for (int i = 0; i < 4; ++i) {
        hA[i] = h_in + (size_t)(m0 + srow[i]) * HH + sgc[i] * 8;
        wB[i] = wperm + (R0 + srow[i]) * HH + sgc[i] * 8;
    }
    const int prow = (tid >> 3) & 31;
    const int pgc = (tid & 7) ^ (prow & 7);
    const u16* wP = wperm + (size_t)(4096 + prow) * HH + pgc * 8;

    int aoff[8], boff[4], poff;
#pragma unroll
    for (int mf = 0; mf < 8; ++mf) {
        int r = qr * 128 + mf * 16 + r16;
        aoff[mf] = r * 64 + ((s4 ^ (r & 7)) * 8);
    }
#pragma unroll
    for (int nf = 0; nf < 4; ++nf) {
        int r = qn * 64 + nf * 16 + r16;
        boff[nf] = r * 64 + ((s4 ^ (r & 7)) * 8);
    }
    {
        int r = qn * 16 + r16;
        poff = r * 64 + ((s4 ^ (r & 7)) * 8);
    }

    f32x4 acc[8][4];
    const int n = nt * 64 + qn * 16 + r16;
    if (!tail) {
#pragma unroll
        for (int nf = 0; nf < 4; ++nf) {
            float bv = bias[nf * HH + n];
#pragma unroll
            for (int mf = 0; mf < 8; ++mf) acc[mf][nf] = (f32x4){bv, bv, bv, bv};
        }
    }
    f32x4 pacc[8];
    const int p = qn * 16 + r16;
    if (my_proj) {
        float pv = (p < INP) ? blin[p] : 0.f;
#pragma unroll
        for (int mf = 0; mf < 8; ++mf) pacc[mf] = (f32x4){pv, pv, pv, pv};
    }

    // ---- prologue: stage tile 0 (x | wx64 | P) via gload_lds ----
    const u16* xA = xpad64 + ((size_t)t * BB + m0) * 64;
#pragma unroll
    for (int i = 0; i < 4; ++i)
        cp16(&lds[ABASE(0) + (tid + i * 512) * 8], xA + (size_t)srow[i] * 64 + sgc[i] * 8);
#pragma unroll
    for (int i = 0; i < 4; ++i)
        cp16(&lds[BBASE(0) + (tid + i * 512) * 8], wx64 + (R0 + srow[i]) * 64 + sgc[i] * 8);
    if (wv < 4) cp16(&lds[PBASE(0) + tid * 8], wP);
    asm volatile("s_waitcnt vmcnt(0)" ::: "memory");
    FENCE;
    __builtin_amdgcn_s_barrier();
    FENCE;

    // ---- pipeline over NK K-tiles, 4 phases each ----
#pragma unroll 1
    for (int j = 0; j < NK; ++j) {
        const int cb = j & 1, nb = cb ^ 1;
        const bool lastj = (j == NK - 1);
        const int ko = j * 64;             // next tile's h K-offset
        const bool dp = my_proj && (j > 0);
        const int cbA = ABASE(cb), cbB = BBASE(cb), cbP = PBASE(cb);
        bf16x8 bfr[4];
        bf16x8 pbf;
#pragma unroll
        for (int ph = 0; ph < 4; ++ph) {
            const int kk = ph >> 1, mg = ph & 1;
            const int kx = kk * 32;
            // --- ds_read cluster for this phase ---
            bf16x8 afr[4];
            if (mg == 0) {
                if (!tail) {
#pragma unroll
                    for (int nf = 0; nf < 4; ++nf)
                        bfr[nf] = ldfrag(&lds[cbB + (boff[nf] ^ kx)]);
                }
                if (dp) pbf = ldfrag(&lds[cbP + (poff ^ kx)]);
            }
#pragma unroll
            for (int i = 0; i < 4; ++i)
                afr[i] = ldfrag(&lds[cbA + (aoff[mg * 4 + i] ^ kx)]);

            // --- stage-issue (spread over phases 0-1) ---
            if (!lastj) {
                if (ph == 0) {
#pragma unroll
                    for (int i = 0; i < 4; ++i)
                        cp16(&lds[ABASE(nb) + (tid + i * 512) * 8], hA[i] + ko);
                    cp16(&lds[BBASE(nb) + tid * 8],           wB[0] + ko);
                    cp16(&lds[BBASE(nb) + (tid + 512) * 8],   wB[1] + ko);
                } else if (ph == 1) {
                    cp16(&lds[BBASE(nb) + (tid + 1024) * 8],  wB[2] + ko);
                    cp16(&lds[BBASE(nb) + (tid + 1536) * 8],  wB[3] + ko);
                    if (wv < 4) cp16(&lds[PBASE(nb) + tid * 8], wP + ko);
                }
            } else if (!tail) {
                // last tile: stage c_old (256x64 f32), 4 slots per phase 0-1
                if (ph < 2) {
#pragma unroll
                    for (int i2 = 0; i2 < 4; ++i2) {
                        const int i = ph * 4 + i2;
                        const int s = tid + i * 512;
                        const int crow = s >> 4, cch = s & 15;
                        const u16* dst = (i < 4) ? &lds[16384 + s * 8]
                                                 : &lds[32768 + s * 8];
                        cp16(dst, c_buf + (size_t)(m0 + crow) * HH + nt * 64 + cch * 4);
                    }
                }
            }
            FENCE;
            __builtin_amdgcn_s_barrier();
            asm volatile("s_waitcnt lgkmcnt(0)" ::: "memory");
            __builtin_amdgcn_sched_barrier(0);
            __builtin_amdgcn_s_setprio(1);
            if (!tail) {
#pragma unroll
                for (int nf = 0; nf < 4; ++nf)
#pragma unroll
                    for (int i = 0; i < 4; ++i)
                        acc[mg * 4 + i][nf] = __builtin_amdgcn_mfma_f32_16x16x32_bf16(
                            afr[i], bfr[nf], acc[mg * 4 + i][nf], 0, 0, 0);
            }
            if (dp) {
#pragma unroll
                for (int i = 0; i < 4; ++i)
                    pacc[mg * 4 + i] = __builtin_amdgcn_mfma_f32_16x16x32_bf16(
                        afr[i], pbf, pacc[mg * 4 + i], 0, 0, 0);
            }
            __builtin_amdgcn_s_setprio(0);
            FENCE;
            if (ph == 3)   // next tile's loads (or c) forced; ~3 phases of cover
                asm volatile("s_waitcnt vmcnt(0)" ::: "memory");
            __builtin_amdgcn_s_barrier();
            FENCE;
        }
    }

    // ---- epilogue: cell in regs -> LDS tiles -> coalesced stores ----
    if (!tail) {
        const int cl = qn * 16 + r16;     // col 0..63 within tile
#pragma unroll
        for (int mf = 0; mf < 8; ++mf)
#pragma unroll
            for (int j = 0; j < 4; ++j) {
                int rl = qr * 128 + mf * 16 + s4 * 4 + j;
                float iv = fast_sigmoid(acc[mf][0][j]);
                float fv = fast_sigmoid(acc[mf][1][j]);
                float gv = fast_tanh(acc[mf][2][j]);
                float ov = fast_sigmoid(acc[mf][3][j]);
                float* crow = (float*)&lds[cBase(rl)];
                float cold = crow[cl];
                float cnew = fv * cold + iv * gv;
                float hnew = ov * fast_tanh(cnew);
                crow[cl] = cnew;                       // c tile in-place
                lds[rl * 64 + cl] = f2bfu(hnew);       // h tile (A0 region)
                if (is_last)
                    __builtin_nontemporal_store(
                        hnew, &h_fin[(size_t)(m0 + rl) * HH + n]);
            }
        __syncthreads();
        // coalesced stores: wave wv owns rows wv*32..wv*32+31; lane = col.
        // c stores PLAIN: stays L2/L3-resident for next launch's c staging.
#pragma unroll 4
        for (int r = 0; r < 32; ++r) {
            const int rl = wv * 32 + r;
            const size_t gi = (size_t)(m0 + rl) * HH + nt * 64 + lane;
            c_buf[gi] = ((float*)&lds[cBase(rl)])[lane];
            h_out[gi] = lds[rl * 64 + lane];
        }
    }
    // ---- proj store: out_{t-1} ----
    if (my_proj && t > 0 && p < INP) {
#pragma unroll
        for (int mf = 0; mf < 8; ++mf)
#pragma unroll
            for (int j = 0; j < 4; ++j) {
                int row = m0 + qr * 128 + mf * 16 + s4 * 4 + j;
                __builtin_nontemporal_store(
                    pacc[mf][j], &outp[((size_t)row * TT + (t - 1)) * INP + p]);
            }
    }
}

// ---------------- launch ----------------
extern "C" void kernel_launch(void* const* d_in, const int* in_sizes, int n_in,
                              void* d_out, int out_size, void* d_ws, size_t ws_size,
                              hipStream_t stream)
{
    const float* x    = (const float*)d_in[0];
    const float* Wih  = (const float*)d_in[1];
    const float* Whh  = (const float*)d_in[2];
    const float* bih  = (const float*)d_in[3];
    const float* bhh  = (const float*)d_in[4];
    const float* Wlin = (const float*)d_in[5];
    const float* blin = (const float*)d_in[6];
    float* out = (float*)d_out;

    char* ws = (char*)d_ws;
    u16* hb0     = (u16*)(ws);                     //  8,388,608 B
    u16* hb1     = (u16*)(ws +  8388608);          //  8,388,608 B
    u16* xpad64  = (u16*)(ws + 16777216);          // 10,485,760 B (20 t-slots x 64)
    u16* wperm   = (u16*)(ws + 27262976);          //  8,454,144 B (4128 x 1024)
    u16* wx64    = (u16*)(ws + 35717120);          //    528,384 B (4128 x 64)
    float* bias  = (float*)(ws + 36245504);        //     16,384 B

    float* h_fin = out + (size_t)BB * TT * INP;    // h_fin region
    float* c_buf = h_fin + (size_t)BB * HH;        // c_fin region = c state

    hipFuncSetAttribute((const void*)lstm_step,
                        hipFuncAttributeMaxDynamicSharedMemorySize, LDS_BYTES);

    hipMemsetAsync(c_buf, 0, (size_t)BB * HH * sizeof(float), stream);

    prep_wperm<<<2064, 256, 0, stream>>>(Whh, Wlin, wperm);
    prep_wx64<<<1032, 256, 0, stream>>>(Wih, wx64);
    prep_bias<<<16, 256, 0, stream>>>(bih, bhh, bias);
    prep_x_t<<<128, 256, 0, stream>>>(x, xpad64);

    for (int t = 0; t < TT; ++t) {
        const u16* hin = (t & 1) ? hb1 : hb0;
        u16* hout = (t & 1) ? hb0 : hb1;
        lstm_step<<<256, 512, LDS_BYTES, stream>>>(
            hin, hout, c_buf, wperm, wx64, bias, xpad64, blin, out,
            h_fin, t, (t == TT - 1) ? 1 : 0, 0);
    }
    // tail: out_18 = h_19 @ W_lin^T + b_lin  (h_19 is in hb1 after t=18)
    proj_tail<<<512, 256, 0, stream>>>(hb1, wperm + (size_t)4096 * HH, blin, out);
}

// Round 21
// 1022.064 us; speedup vs baseline: 1.0211x; 1.0211x over previous
//
#include <hip/hip_runtime.h>
#include <hip/hip_bf16.h>

typedef unsigned short u16;
typedef __attribute__((ext_vector_type(8))) __bf16 bf16x8;
typedef __attribute__((ext_vector_type(8))) short short8;
typedef __attribute__((ext_vector_type(4))) float f32x4;

#define BB 4096
#define TT 19
#define INP 17
#define HH 1024
#define NE 4128          // 4096 permuted gate entries + 32 proj rows
#define NT_PROJ 15       // proj rows are used by nt==15 blocks

// u16-unit LDS map (per block, 53,248 B -> 2 blocks/CU):
//   A dbuf 2 x 4096  [0, 8192)      (tile 128 x 32)
//   B dbuf 2 x 8192  [8192, 24576)  (tile 256 x 32)
//   P dbuf 2 x 1024  [24576, 26624) (tile  32 x 32)
// epilogue reuse (AFTER the final K-tile barrier, all bufs dead):
//   h tile [128][64] u16 -> A0+A1  [0, 8192)
//   c tile [128][64] f32 -> B0+B1  [8192, 24576)  (exactly 32 KB)
#define ABASE(b) ((b) * 4096)
#define BBASE(b) (8192 + (b) * 8192)
#define PBASE(b) (24576 + (b) * 1024)
#define LDS_BYTES 53248

#define FENCE asm volatile("" ::: "memory")

__device__ __forceinline__ u16 f2bfu(float f) {
    __hip_bfloat16 b = __float2bfloat16(f);
    return __builtin_bit_cast(unsigned short, b);
}
__device__ __forceinline__ float bfu2f(u16 u) {
    unsigned int x = ((unsigned int)u) << 16;
    return __builtin_bit_cast(float, x);
}
__device__ __forceinline__ float fast_sigmoid(float x) {
    return 1.f / (1.f + __expf(-x));
}
__device__ __forceinline__ float fast_tanh(float x) {
    float e = __expf(2.f * x);
    return (e - 1.f) / (e + 1.f);
}
__device__ __forceinline__ bf16x8 ldfrag(const u16* p) {
    return __builtin_bit_cast(bf16x8, *(const short8*)p);
}
// 16B-chunk swizzle within a 32-elem row (involution), r10-verified
__device__ __forceinline__ int fsw(int r) { return (r ^ (r >> 2)) & 3; }
// c-tile row base in u16 units (contiguous across B0+B1, dead post-loop)
__device__ __forceinline__ int cBase(int row) { return 8192 + row * 128; }
// async 16B global -> LDS (linear dest = wave base + lane*16)
__device__ __forceinline__ void cp16(const u16* l, const void* g) {
    __builtin_amdgcn_global_load_lds(
        (const __attribute__((address_space(1))) unsigned int*)g,
        (__attribute__((address_space(3))) unsigned int*)l, 16, 0, 0);
}

// ---------------- prep kernels ----------------
// wperm[NE][HH]: entry r of tile nt -> gate (r>>4)&3, hcol nt*64+(r>>6)*16+(r&15);
// rows 4096..4127 = W_lin rows (17 real + zero pad). grid MUST be 2064.
__global__ void prep_wperm(const float* __restrict__ Whh, const float* __restrict__ Wlin,
                           u16* __restrict__ wperm) {
    size_t idx = ((size_t)blockIdx.x * 256 + threadIdx.x) * 8;
    int R = (int)(idx >> 10);
    int k = (int)(idx & 1023);
    const float* src = nullptr;
    if (R < 4096) {
        int nt = R >> 8, r = R & 255;
        int qn = r >> 6, nf = (r >> 4) & 3, cj = r & 15;
        int hcol = nt * 64 + qn * 16 + cj;
        src = Whh + ((size_t)(nf * HH + hcol)) * HH + k;
    } else if (R - 4096 < INP) {
        src = Wlin + (size_t)(R - 4096) * HH + k;
    }
#pragma unroll
    for (int e = 0; e < 8; ++e) wperm[idx + e] = src ? f2bfu(src[e]) : (u16)0;
}

// wx32[NE][32]: same row permutation of W_ih, K padded 17->32. grid 516.
__global__ void prep_wx(const float* __restrict__ Wih, u16* __restrict__ wx32) {
    int idx = blockIdx.x * 256 + threadIdx.x;
    int R = idx >> 5, k = idx & 31;
    u16 v = 0;
    if (R < 4096 && k < INP) {
        int nt = R >> 8, r = R & 255;
        int qn = r >> 6, nf = (r >> 4) & 3, cj = r & 15;
        int hcol = nt * 64 + qn * 16 + cj;
        v = f2bfu(Wih[(size_t)(nf * HH + hcol) * INP + k]);
    }
    wx32[idx] = v;
}

// bias[4096] = b_ih + b_hh. grid 16.
__global__ void prep_bias(const float* __restrict__ bih, const float* __restrict__ bhh,
                          float* __restrict__ bias) {
    int idx = blockIdx.x * 256 + threadIdx.x;
    bias[idx] = bih[idx] + bhh[idx];
}

// xpad[t][b][32] via LDS transpose: block stages 32 batch rows (32x323 f32)
// coalesced, then writes 19 t-slots as contiguous 2 KB runs. grid MUST be 128.
__global__ __launch_bounds__(256) void prep_x_t(const float* __restrict__ x,
                                                u16* __restrict__ xpad) {
    __shared__ float sx[32 * 323];          // 41,344 B
    const int tid = threadIdx.x;
    const int b0 = blockIdx.x * 32;
    for (int j = tid; j < 32 * 323; j += 256)
        sx[j] = x[(size_t)b0 * 323 + j];
    __syncthreads();
    for (int j = tid; j < TT * 32 * 32; j += 256) {
        int tt = j >> 10;                   // 0..18
        int r = (j >> 5) & 31;
        int c = j & 31;
        u16 v = (c < INP) ? f2bfu(sx[r * 323 + tt * 17 + c]) : (u16)0;
        xpad[((size_t)tt * BB + b0 + r) * 32 + c] = v;
    }
}

// tail projection: out_18 = h_19 @ W_lin^T + b_lin. grid 512 x 8 rows.
__global__ __launch_bounds__(256) void proj_tail(
    const u16* __restrict__ h, const u16* __restrict__ wlin,
    const float* __restrict__ blin, float* __restrict__ outp)
{
    __shared__ u16 sW[INP * 1032];          // 35,088 B
    __shared__ u16 sh[8 * 1032];            // 16,512 B
    const int tid = threadIdx.x;
    const int b0 = blockIdx.x * 8;
    for (int j = tid; j < INP * 128; j += 256) {
        int r = j >> 7, c = j & 127;
        *(short8*)&sW[r * 1032 + c * 8] = *(const short8*)&wlin[(size_t)r * HH + c * 8];
    }
    for (int j = tid; j < 8 * 128; j += 256) {
        int r = j >> 7, c = j & 127;
        *(short8*)&sh[r * 1032 + c * 8] = *(const short8*)&h[(size_t)(b0 + r) * HH + c * 8];
    }
    __syncthreads();
    const int row = tid >> 5;               // 0..7
    const int il = tid & 31;                // active < 17
    if (il < INP) {
        float sum = 0.f;
        for (int k = 0; k < HH; k += 8) {
            short8 hv = *(const short8*)&sh[row * 1032 + k];
            short8 wv = *(const short8*)&sW[il * 1032 + k];
#pragma unroll
            for (int e = 0; e < 8; ++e)
                sum += bfu2f((u16)hv[e]) * bfu2f((u16)wv[e]);
        }
        outp[((size_t)(b0 + row) * TT + 18) * INP + il] = sum + blin[il];
    }
}

// ---- fused step kernel: 128x256 tile, BK=32, 2 blocks/CU TLP pipeline ----
// grid 512 = 32 mt x 16 nt (XCD-chunked: xcd owns nt {2xcd, 2xcd+1}).
// 256 threads = 4 waves; wave qn owns all 128 rows x 64 entries (8 mf x 4 nf).
// 33 K-tiles (x + 32 h), double-buffered, counted vmcnt(6|8). Epilogue:
// c_old staged AFTER the final barrier (all LDS dead; fixes r20's race of
// c landing in live B0); cell in regs; coalesced h/c stores.
__global__ __launch_bounds__(256, 2) void lstm_step(
    const u16* __restrict__ h_in, u16* __restrict__ h_out,
    float* __restrict__ c_buf, const u16* __restrict__ wperm,
    const u16* __restrict__ wx32, const float* __restrict__ bias,
    const u16* __restrict__ xpad, const float* __restrict__ blin,
    float* __restrict__ outp, float* __restrict__ h_fin,
    int t, int is_last)
{
    extern __shared__ u16 lds[];

    const int tid = threadIdx.x;
    const int lane = tid & 63;
    const int wv = tid >> 6;          // 0..3
    const int qn = wv;                // entry quarter
    const int r16 = lane & 15, s4 = lane >> 4;

    const int xcd = blockIdx.x & 7, local = blockIdx.x >> 3;   // 0..63
    const int nt = 2 * xcd + (local >> 5);
    const int mt = local & 31;
    const int m0 = mt * 128;
    const size_t R0 = (size_t)nt * 256;
    const bool my_proj = (nt == NT_PROJ) && (qn < 2);
    const int NK = (t > 0) ? 33 : 1;  // t==0: gates = x@Wih + b only

    // A staging: 2 slots (d = tid + i*256, d<512): row=d>>2, chunk=d&3
    // B staging: 4 slots (d<1024): row=d>>2.  P (wv0): 2 slots (d = lane+i*64).
    const u16* hA[2];
    const u16* wB[4];
#pragma unroll
    for (int i = 0; i < 2; ++i) {
        int d = tid + i * 256, row = d >> 2;
        hA[i] = h_in + (size_t)(m0 + row) * HH + (((d & 3) ^ fsw(row)) & 3) * 8;
    }
#pragma unroll
    for (int i = 0; i < 4; ++i) {
        int d = tid + i * 256, row = d >> 2;
        wB[i] = wperm + (R0 + row) * HH + (((d & 3) ^ fsw(row)) & 3) * 8;
    }
    const u16* wP[2];
#pragma unroll
    for (int i = 0; i < 2; ++i) {
        int d = lane + i * 64, row = d >> 2;
        wP[i] = wperm + (size_t)(4096 + row) * HH + (((d & 3) ^ fsw(row)) & 3) * 8;
    }

    // fragment read offsets (swizzled, BK=32 rows)
    int aoff[8], boff[4], poff;
#pragma unroll
    for (int mf = 0; mf < 8; ++mf) {
        int r = mf * 16 + r16;
        aoff[mf] = r * 32 + ((s4 ^ fsw(r)) & 3) * 8;
    }
#pragma unroll
    for (int nf = 0; nf < 4; ++nf) {
        int r = qn * 64 + nf * 16 + r16;
        boff[nf] = r * 32 + ((s4 ^ fsw(r)) & 3) * 8;
    }
    {
        int r = qn * 16 + r16;
        poff = r * 32 + ((s4 ^ fsw(r)) & 3) * 8;
    }

    // acc init with bias
    f32x4 acc[8][4];
    const int n = nt * 64 + qn * 16 + r16;
#pragma unroll
    for (int nf = 0; nf < 4; ++nf) {
        float bv = bias[nf * HH + n];
#pragma unroll
        for (int mf = 0; mf < 8; ++mf) acc[mf][nf] = (f32x4){bv, bv, bv, bv};
    }
    f32x4 pacc[8];
    const int p = qn * 16 + r16;
    if (my_proj) {
        float pv = (p < INP) ? blin[p] : 0.f;
#pragma unroll
        for (int mf = 0; mf < 8; ++mf) pacc[mf] = (f32x4){pv, pv, pv, pv};
    }

    // ---- prologue: stage tile 0 (x | wx32 | P) ----
#pragma unroll
    for (int i = 0; i < 2; ++i) {
        int d = tid + i * 256, row = d >> 2;
        cp16(&lds[ABASE(0) + d * 8],
             xpad + ((size_t)t * BB + m0 + row) * 32 + (((d & 3) ^ fsw(row)) & 3) * 8);
    }
#pragma unroll
    for (int i = 0; i < 4; ++i) {
        int d = tid + i * 256, row = d >> 2;
        cp16(&lds[BBASE(0) + d * 8],
             wx32 + (R0 + row) * 32 + (((d & 3) ^ fsw(row)) & 3) * 8);
    }
    if (wv == 0) {
#pragma unroll
        for (int i = 0; i < 2; ++i) cp16(&lds[PBASE(0) + (lane + i * 64) * 8], wP[i]);
    }

    // ---- pipeline over NK K-tiles ----
    for (int j = 0; j < NK; ++j) {
        const int cb = j & 1, nb = cb ^ 1;
        if (j < NK - 1) {
            const int ko = j * 32;        // h K-offset of tile j+1
#pragma unroll
            for (int i = 0; i < 2; ++i)
                cp16(&lds[ABASE(nb) + (tid + i * 256) * 8], hA[i] + ko);
#pragma unroll
            for (int i = 0; i < 4; ++i)
                cp16(&lds[BBASE(nb) + (tid + i * 256) * 8], wB[i] + ko);
            if (wv == 0) {
#pragma unroll
                for (int i = 0; i < 2; ++i)
                    cp16(&lds[PBASE(nb) + (lane + i * 64) * 8], wP[i] + ko);
                asm volatile("s_waitcnt vmcnt(8)" ::: "memory");
            } else {
                asm volatile("s_waitcnt vmcnt(6)" ::: "memory");
            }
        } else {
            asm volatile("s_waitcnt vmcnt(0)" ::: "memory");
        }
        __builtin_amdgcn_s_barrier();
        FENCE;

        const int cbA = ABASE(cb), cbB = BBASE(cb), cbP = PBASE(cb);
        const bool do_p = my_proj && (j > 0);
        __builtin_amdgcn_s_setprio(1);
        bf16x8 b[4];
#pragma unroll
        for (int nf = 0; nf < 4; ++nf) b[nf] = ldfrag(&lds[cbB + boff[nf]]);
        bf16x8 pb;
        if (do_p) pb = ldfrag(&lds[cbP + poff]);
#pragma unroll
        for (int mf = 0; mf < 8; ++mf) {
            bf16x8 a = ldfrag(&lds[cbA + aoff[mf]]);
#pragma unroll
            for (int nf = 0; nf < 4; ++nf)
                acc[mf][nf] = __builtin_amdgcn_mfma_f32_16x16x32_bf16(
                    a, b[nf], acc[mf][nf], 0, 0, 0);
            if (do_p)
                pacc[mf] = __builtin_amdgcn_mfma_f32_16x16x32_bf16(
                    a, pb, pacc[mf], 0, 0, 0);
        }
        __builtin_amdgcn_s_setprio(0);
        FENCE;
        __builtin_amdgcn_s_barrier();
        FENCE;
    }

    // ---- epilogue: stage c_old (ALL LDS dead now), cell, coalesced stores ----
    {
        // c_old 128x64 f32 = 2048 16B-slots -> B0+B1 [8192, 24576), coalesced
#pragma unroll
        for (int i = 0; i < 8; ++i) {
            const int s = tid + i * 256;
            const int crow = s >> 4, cch = s & 15;
            cp16(&lds[8192 + s * 8],
                 c_buf + (size_t)(m0 + crow) * HH + nt * 64 + cch * 4);
        }
        asm volatile("s_waitcnt vmcnt(0)" ::: "memory");
        __syncthreads();                  // c tile resident for all
        const int cl = qn * 16 + r16;     // col 0..63 within tile
#pragma unroll
        for (int mf = 0; mf < 8; ++mf)
#pragma unroll
            for (int j = 0; j < 4; ++j) {
                int rl = mf * 16 + s4 * 4 + j;         // 0..127
                float iv = fast_sigmoid(acc[mf][0][j]);
                float fv = fast_sigmoid(acc[mf][1][j]);
                float gv = fast_tanh(acc[mf][2][j]);
                float ov = fast_sigmoid(acc[mf][3][j]);
                float* crow = (float*)&lds[cBase(rl)];
                float cold = crow[cl];
                float cnew = fv * cold + iv * gv;
                float hnew = ov * fast_tanh(cnew);
                crow[cl] = cnew;                       // c tile in-place
                lds[rl * 64 + cl] = f2bfu(hnew);       // h tile (A bufs)
                if (is_last)
                    __builtin_nontemporal_store(
                        hnew, &h_fin[(size_t)(m0 + rl) * HH + n]);
            }
        __syncthreads();
        // coalesced stores: wave wv owns rows wv*32..+31; lane = col.
#pragma unroll 4
        for (int r = 0; r < 32; ++r) {
            const int rl = wv * 32 + r;
            const size_t gi = (size_t)(m0 + rl) * HH + nt * 64 + lane;
            c_buf[gi] = ((float*)&lds[cBase(rl)])[lane];
            h_out[gi] = lds[rl * 64 + lane];
        }
    }
    // ---- proj store: out_{t-1} ----
    if (my_proj && t > 0 && p < INP) {
#pragma unroll
        for (int mf = 0; mf < 8; ++mf)
#pragma unroll
            for (int j = 0; j < 4; ++j) {
                int row = m0 + mf * 16 + s4 * 4 + j;
                __builtin_nontemporal_store(
                    pacc[mf][j], &outp[((size_t)row * TT + (t - 1)) * INP + p]);
            }
    }
}

// ---------------- launch ----------------
extern "C" void kernel_launch(void* const* d_in, const int* in_sizes, int n_in,
                              void* d_out, int out_size, void* d_ws, size_t ws_size,
                              hipStream_t stream)
{
    const float* x    = (const float*)d_in[0];
    const float* Wih  = (const float*)d_in[1];
    const float* Whh  = (const float*)d_in[2];
    const float* bih  = (const float*)d_in[3];
    const float* bhh  = (const float*)d_in[4];
    const float* Wlin = (const float*)d_in[5];
    const float* blin = (const float*)d_in[6];
    float* out = (float*)d_out;

    char* ws = (char*)d_ws;
    u16* hb0     = (u16*)(ws);                     //  8,388,608 B
    u16* hb1     = (u16*)(ws +  8388608);          //  8,388,608 B
    u16* xpad    = (u16*)(ws + 16777216);          //  4,980,736 B (19 t-slots)
    u16* wperm   = (u16*)(ws + 21757952);          //  8,454,144 B (4128 x 1024)
    u16* wx32    = (u16*)(ws + 30212096);          //    264,192 B (4128 x 32)
    float* bias  = (float*)(ws + 30476288);        //     16,384 B

    float* h_fin = out + (size_t)BB * TT * INP;    // h_fin region
    float* c_buf = h_fin + (size_t)BB * HH;        // c_fin region = c state

    hipFuncSetAttribute((const void*)lstm_step,
                        hipFuncAttributeMaxDynamicSharedMemorySize, LDS_BYTES);

    hipMemsetAsync(c_buf, 0, (size_t)BB * HH * sizeof(float), stream);

    prep_wperm<<<2064, 256, 0, stream>>>(Whh, Wlin, wperm);
    prep_wx<<<516, 256, 0, stream>>>(Wih, wx32);
    prep_bias<<<16, 256, 0, stream>>>(bih, bhh, bias);
    prep_x_t<<<128, 256, 0, stream>>>(x, xpad);

    for (int t = 0; t < TT; ++t) {
        const u16* hin = (t & 1) ? hb1 : hb0;
        u16* hout = (t & 1) ? hb0 : hb1;
        lstm_step<<<512, 256, LDS_BYTES, stream>>>(
            hin, hout, c_buf, wperm, wx32, bias, xpad, blin, out,
            h_fin, t, (t == TT - 1) ? 1 : 0);
    }
    // tail: out_18 = h_19 @ W_lin^T + b_lin  (h_19 is in hb1 after t=18)
    proj_tail<<<512, 256, 0, stream>>>(hb1, wperm + (size_t)4096 * HH, blin, out);
}